// Round 14
// baseline (1159.774 us; speedup 1.0000x reference)
//
#include <hip/hip_runtime.h>
#include <math.h>

#define NB   16
#define NP   4096
#define NC   64
#define NS   1024
#define NK   32
#define NOUT 128

typedef unsigned long long u64;
typedef unsigned int u32;
typedef unsigned short u16;
typedef __attribute__((ext_vector_type(8))) short s16x8;
typedef __attribute__((ext_vector_type(4))) float f32x4;

__device__ inline u64 umin64(u64 a, u64 b) { return a < b ? a : b; }
__device__ inline u64 umax64(u64 a, u64 b) { return a > b ? a : b; }

__device__ inline u16 f2bf(float f) {
  u32 x = __float_as_uint(f);
  return (u16)((x + 0x7fffu + ((x >> 16) & 1u)) >> 16);
}
__device__ inline u32 pack2bf(float a, float b) {
  return (u32)f2bf(a) | ((u32)f2bf(b) << 16);
}

__device__ inline float d2exact(float ax, float ay, float az,
                                float qx, float qy, float qz) {
  float dx = __fsub_rn(ax, qx), dy = __fsub_rn(ay, qy), dz = __fsub_rn(az, qz);
  return __fadd_rn(__fadd_rn(__fmul_rn(dx, dx), __fmul_rn(dy, dy)),
                   __fmul_rn(dz, dz));
}

// ---------------------------------------------------------------------------
// DPP wave64 reductions (row_shr 1/2/4/8 toward lane15, bcast15, bcast31 ->
// result in lane 63). Verified rounds 5-13.
// ---------------------------------------------------------------------------
// 5-tuple max: key (u64) + 3 coord words ride along with the winner.
#define DPP_LVL_MAX5(CTRL)                                                    \
  {                                                                           \
    u32 klo = (u32)key, khi = (u32)(key >> 32);                               \
    u32 plo = (u32)__builtin_amdgcn_update_dpp((int)klo, (int)klo, CTRL, 0xF, 0xF, false); \
    u32 phi = (u32)__builtin_amdgcn_update_dpp((int)khi, (int)khi, CTRL, 0xF, 0xF, false); \
    u32 pxb = (u32)__builtin_amdgcn_update_dpp((int)xb, (int)xb, CTRL, 0xF, 0xF, false); \
    u32 pyb = (u32)__builtin_amdgcn_update_dpp((int)yb, (int)yb, CTRL, 0xF, 0xF, false); \
    u32 pzb = (u32)__builtin_amdgcn_update_dpp((int)zb, (int)zb, CTRL, 0xF, 0xF, false); \
    u64 ok = ((u64)phi << 32) | plo;                                          \
    if (ok > key) { key = ok; xb = pxb; yb = pyb; zb = pzb; }                 \
  }
__device__ inline void dpp_wavemax5(u64& key, u32& xb, u32& yb, u32& zb) {
  DPP_LVL_MAX5(0x111) DPP_LVL_MAX5(0x112) DPP_LVL_MAX5(0x114)
  DPP_LVL_MAX5(0x118) DPP_LVL_MAX5(0x142) DPP_LVL_MAX5(0x143)
}

#define DPP_LVL_MIN(CTRL)                                                     \
  {                                                                           \
    u32 lo = (u32)key, hi = (u32)(key >> 32);                                 \
    u32 plo = (u32)__builtin_amdgcn_update_dpp((int)lo, (int)lo, CTRL, 0xF, 0xF, false); \
    u32 phi = (u32)__builtin_amdgcn_update_dpp((int)hi, (int)hi, CTRL, 0xF, 0xF, false); \
    u64 ok = ((u64)phi << 32) | plo;                                          \
    key = (ok < key) ? ok : key;                                              \
  }
__device__ inline u64 dpp_wavemin_bcast_u64(u64 key) {
  DPP_LVL_MIN(0x111) DPP_LVL_MIN(0x112) DPP_LVL_MIN(0x114)
  DPP_LVL_MIN(0x118) DPP_LVL_MIN(0x142) DPP_LVL_MIN(0x143)
  u32 lo = (u32)__builtin_amdgcn_readlane((int)(u32)key, 63);
  u32 hi = (u32)__builtin_amdgcn_readlane((int)(u32)(key >> 32), 63);
  return ((u64)hi << 32) | lo;  // uniform across wave
}

#define DPP_FMAX_STAGE(CTRL)                                                  \
  do {                                                                        \
    _Pragma("unroll")                                                         \
    for (int mt = 0; mt < 8; ++mt) {                                          \
      _Pragma("unroll")                                                       \
      for (int r = 0; r < 4; ++r) {                                           \
        int vi = __float_as_int(m[mt][r]);                                    \
        int ov = __builtin_amdgcn_update_dpp(vi, vi, CTRL, 0xF, 0xF, false);  \
        m[mt][r] = fmaxf(m[mt][r], __int_as_float(ov));                       \
      }                                                                       \
    }                                                                         \
  } while (0)

__device__ inline void ins4(u64& b0, u64& b1, u64& b2, u64& b3, u64 k) {
  u64 m0 = umax64(b0, k); b0 = umin64(b0, k);
  u64 m1 = umax64(b1, m0); b1 = umin64(b1, m0);
  u64 m2 = umax64(b2, m1); b2 = umin64(b2, m1);
  b3 = umin64(b3, m2);
}

// ---------------------------------------------------------------------------
// FPS: one block per cloud, 256 threads (4 waves, 1/SIMD), 16 pts/thread in
// registers. Coordinates of the per-lane best point ride through the DPP
// argmax (5-tuple), so no 48KB LDS point cache and no dependent lx[far]
// lookup. tid 0 writes pos_q in-loop (fire-and-forget). Bit-exact math.
// Producer body verified correct in fused rounds 9-11.
// ---------------------------------------------------------------------------
__global__ __launch_bounds__(256) void fps_kernel(const float* __restrict__ pos,
                                                  float* __restrict__ pos_q,
                                                  float* __restrict__ batch_q) {
  const int b = blockIdx.x;
  const int tid = threadIdx.x;
  const int wave = tid >> 6;
  const float* pb = pos + (size_t)b * NP * 3;

  __shared__ uint4 s_k[2][4];   // per-wave {klo, khi, xbits, ybits}
  __shared__ u32  s_z[2][4];    // per-wave zbits

  float px[16], py[16], pz[16], dist[16];
#pragma unroll
  for (int i = 0; i < 16; ++i) {
    int p = i * 256 + tid;
    px[i] = pb[p * 3 + 0];
    py[i] = pb[p * 3 + 1];
    pz[i] = pb[p * 3 + 2];
    dist[i] = __builtin_inff();
  }
  float fx = pb[0], fy = pb[1], fz = pb[2];

  for (int s = 0; s < NS; ++s) {
    if (tid == 0) {
      float* pq = pos_q + (size_t)(b * NS + s) * 3;
      pq[0] = fx; pq[1] = fy; pq[2] = fz;
    }

    float bv = -1.0f; int bp = 0;
    float bx = 0.f, by = 0.f, bz = 0.f;
#pragma unroll
    for (int i = 0; i < 16; ++i) {
      float dx = __fsub_rn(px[i], fx);
      float dy = __fsub_rn(py[i], fy);
      float dz = __fsub_rn(pz[i], fz);
      float d = __fadd_rn(__fadd_rn(__fmul_rn(dx, dx), __fmul_rn(dy, dy)),
                          __fmul_rn(dz, dz));
      d = fminf(dist[i], d);
      dist[i] = d;
      if (d > bv) { bv = d; bp = i * 256 + tid; bx = px[i]; by = py[i]; bz = pz[i]; }
    }

    u64 key = ((u64)__float_as_uint(bv) << 32) | (u32)(NP - 1 - bp);
    u32 xb = __float_as_uint(bx), yb = __float_as_uint(by),
        zb = __float_as_uint(bz);
    dpp_wavemax5(key, xb, yb, zb);
    if ((tid & 63) == 63) {
      s_k[s & 1][wave] = make_uint4((u32)key, (u32)(key >> 32), xb, yb);
      s_z[s & 1][wave] = zb;
    }
    __syncthreads();

    uint4 a0 = s_k[s & 1][0], a1 = s_k[s & 1][1];
    uint4 a2 = s_k[s & 1][2], a3 = s_k[s & 1][3];
    u32 z0 = s_z[s & 1][0], z1 = s_z[s & 1][1];
    u32 z2 = s_z[s & 1][2], z3 = s_z[s & 1][3];
    u64 k0 = ((u64)a0.y << 32) | a0.x;
    u64 k1 = ((u64)a1.y << 32) | a1.x;
    u64 k2 = ((u64)a2.y << 32) | a2.x;
    u64 k3 = ((u64)a3.y << 32) | a3.x;
    if (k1 > k0) { k0 = k1; a0 = a1; z0 = z1; }
    if (k3 > k2) { k2 = k3; a2 = a3; z2 = z3; }
    if (k2 > k0) { k0 = k2; a0 = a2; z0 = z2; }
    fx = __uint_as_float(a0.z);
    fy = __uint_as_float(a0.w);
    fz = __uint_as_float(z0);
  }

  for (int s = tid; s < NS; s += 256)
    batch_q[b * NS + s] = (float)b;
}

// ---------------------------------------------------------------------------
// kNN: one wave per query (round-7 verbatim, passing). Coalesced float4
// scan, sorted top-4/lane, 32 DPP-min extractions + owner pop, rare refill.
// Owner of point p: lane (p>>2)&63; slot = (p>>8)*4 + (p&3).
// ---------------------------------------------------------------------------
__global__ __launch_bounds__(64) void knn_kernel(const float* __restrict__ pos,
                                                 const float* __restrict__ pos_q,
                                                 int* __restrict__ nbr) {
  const u64 KMAX = ~0ull;
  const int q = blockIdx.x;
  const int b = q >> 10;
  const int lane = threadIdx.x;
  const float* pb = pos + (size_t)b * NP * 3;
  const float qx = pos_q[q * 3 + 0];
  const float qy = pos_q[q * 3 + 1];
  const float qz = pos_q[q * 3 + 2];

  u64 b0 = KMAX, b1 = KMAX, b2 = KMAX, b3 = KMAX;
#pragma unroll 4
  for (int gg = 0; gg < 16; ++gg) {
    int p = gg * 256 + lane * 4;
    const float* s = pb + (size_t)p * 3;
    float4 v0 = *(const float4*)(s);
    float4 v1 = *(const float4*)(s + 4);
    float4 v2 = *(const float4*)(s + 8);
    float d0 = d2exact(v0.x, v0.y, v0.z, qx, qy, qz);
    float d1 = d2exact(v0.w, v1.x, v1.y, qx, qy, qz);
    float d2 = d2exact(v1.z, v1.w, v2.x, qx, qy, qz);
    float d3 = d2exact(v2.y, v2.z, v2.w, qx, qy, qz);
    ins4(b0, b1, b2, b3, ((u64)__float_as_uint(d0) << 32) | (u32)(p + 0));
    ins4(b0, b1, b2, b3, ((u64)__float_as_uint(d1) << 32) | (u32)(p + 1));
    ins4(b0, b1, b2, b3, ((u64)__float_as_uint(d2) << 32) | (u32)(p + 2));
    ins4(b0, b1, b2, b3, ((u64)__float_as_uint(d3) << 32) | (u32)(p + 3));
  }

  u64 exmask = 0ull;
  for (int r = 0; r < NK; ++r) {
    u64 kmin = dpp_wavemin_bcast_u64(b0);
    u32 p = (u32)kmin;
    if (lane == 0) nbr[q * NK + r] = (int)p;
    if (((p >> 2) & 63u) == (u32)lane) {
      b0 = b1; b1 = b2; b2 = b3; b3 = KMAX;
      exmask |= 1ull << (((p >> 8) << 2) | (p & 3u));
      if (b0 == KMAX) {
        for (int gg = 0; gg < 16; ++gg) {
          int pp = gg * 256 + lane * 4;
          const float* s = pb + (size_t)pp * 3;
          float4 v0 = *(const float4*)(s);
          float4 v1 = *(const float4*)(s + 4);
          float4 v2 = *(const float4*)(s + 8);
          float dd[4];
          dd[0] = d2exact(v0.x, v0.y, v0.z, qx, qy, qz);
          dd[1] = d2exact(v0.w, v1.x, v1.y, qx, qy, qz);
          dd[2] = d2exact(v1.z, v1.w, v2.x, qx, qy, qz);
          dd[3] = d2exact(v2.y, v2.z, v2.w, qx, qy, qz);
#pragma unroll
          for (int rr = 0; rr < 4; ++rr) {
            int slot = gg * 4 + rr;
            if ((exmask >> slot) & 1ull) continue;
            ins4(b0, b1, b2, b3,
                 ((u64)__float_as_uint(dd[rr]) << 32) | (u32)(pp + rr));
          }
        }
      }
    }
  }
}

// ---------------------------------------------------------------------------
// Weight prepack (round-7 verbatim): W -> bf16 MFMA A-fragments in d_ws.
// ---------------------------------------------------------------------------
#define WF_L2 6144
#define WF_L3 10240
#define WF_TOT 18432

__global__ __launch_bounds__(256) void prep_kernel(
    const float* __restrict__ W1, const float* __restrict__ W2,
    const float* __restrict__ W3, u16* __restrict__ wf) {
  int flat = blockIdx.x * 256 + threadIdx.x;
  if (flat >= WF_TOT) return;
  float val;
  int j = flat & 7, lane = (flat >> 3) & 63, t = flat >> 9;
  int k8 = 8 * (lane >> 4) + j, li = lane & 15;
  if (flat < WF_L2) {
    int kc = t % 3, mt = t / 3;
    int k = kc * 32 + k8;
    val = (k < 67) ? W1[k * 64 + mt * 16 + li] : 0.0f;
  } else if (flat < WF_L3) {
    t -= WF_L2 >> 9;
    int kc = t & 1, mt = t >> 1;
    val = W2[(kc * 32 + k8) * 64 + mt * 16 + li];
  } else {
    t -= WF_L3 >> 9;
    int kc = t & 1, mt = t >> 1;
    val = W3[(kc * 32 + k8) * 128 + mt * 16 + li];
  }
  wf[flat] = f2bf(val);
}

// ---------------------------------------------------------------------------
// PointNetConv via MFMA 16x16x32 bf16 (round-7 verbatim, passing).
// One query per wave, 4 waves/block, wave-private LDS bounce between layers.
// ---------------------------------------------------------------------------
#define HST 72

__global__ __launch_bounds__(256) void conv_kernel(
    const float* __restrict__ x, const float* __restrict__ pos,
    const u16* __restrict__ wf,
    const float* __restrict__ b1, const float* __restrict__ b2,
    const float* __restrict__ b3,
    const int* __restrict__ nbr, const float* __restrict__ pos_q,
    float* __restrict__ out) {
  __shared__ u16 Hs[4][32][HST];

  const int tid = threadIdx.x, wave = tid >> 6, lane = tid & 63;
  const int q = blockIdx.x * 4 + wave;
  const int b = q >> 10;
  const int g = lane >> 4, li = lane & 15;

  const int n0 = nbr[q * NK + li];
  const int n1 = nbr[q * NK + li + 16];
  const float qx = pos_q[q * 3 + 0];
  const float qy = pos_q[q * 3 + 1];
  const float qz = pos_q[q * 3 + 2];

  uint4 bf1[2][3];
  {
    const float* xb = x + (size_t)b * NP * NC;
#pragma unroll
    for (int nt = 0; nt < 2; ++nt) {
      const float* s = xb + (size_t)(nt ? n1 : n0) * NC + 8 * g;
#pragma unroll
      for (int kc = 0; kc < 2; ++kc) {
        float4 v0 = *(const float4*)(s + kc * 32);
        float4 v1 = *(const float4*)(s + kc * 32 + 4);
        bf1[nt][kc] = make_uint4(pack2bf(v0.x, v0.y), pack2bf(v0.z, v0.w),
                                 pack2bf(v1.x, v1.y), pack2bf(v1.z, v1.w));
      }
      const float* pp = pos + ((size_t)b * NP + (nt ? n1 : n0)) * 3;
      float rx = __fsub_rn(pp[0], qx);
      float ry = __fsub_rn(pp[1], qy);
      float rz = __fsub_rn(pp[2], qz);
      uint4 w = make_uint4(0u, 0u, 0u, 0u);
      if (g == 0) { w.x = pack2bf(rx, ry); w.y = pack2bf(rz, 0.0f); }
      bf1[nt][2] = w;
    }
  }

  const uint4* wf4 = (const uint4*)wf;

  // layer 1
  {
    f32x4 acc[4][2];
#pragma unroll
    for (int mt = 0; mt < 4; ++mt) {
      float4 bb = *(const float4*)(b1 + mt * 16 + 4 * g);
      acc[mt][0] = f32x4{bb.x, bb.y, bb.z, bb.w};
      acc[mt][1] = acc[mt][0];
    }
#pragma unroll
    for (int mt = 0; mt < 4; ++mt)
#pragma unroll
      for (int kc = 0; kc < 3; ++kc) {
        uint4 aw = wf4[(mt * 3 + kc) * 64 + lane];
        s16x8 a = __builtin_bit_cast(s16x8, aw);
        acc[mt][0] = __builtin_amdgcn_mfma_f32_16x16x32_bf16(
            a, __builtin_bit_cast(s16x8, bf1[0][kc]), acc[mt][0], 0, 0, 0);
        acc[mt][1] = __builtin_amdgcn_mfma_f32_16x16x32_bf16(
            a, __builtin_bit_cast(s16x8, bf1[1][kc]), acc[mt][1], 0, 0, 0);
      }
#pragma unroll
    for (int mt = 0; mt < 4; ++mt)
#pragma unroll
      for (int nt = 0; nt < 2; ++nt) {
        f32x4 v = acc[mt][nt];
        u32 w0 = pack2bf(fmaxf(v[0], 0.f), fmaxf(v[1], 0.f));
        u32 w1 = pack2bf(fmaxf(v[2], 0.f), fmaxf(v[3], 0.f));
        *(uint2*)&Hs[wave][li + 16 * nt][mt * 16 + 4 * g] = make_uint2(w0, w1);
      }
  }
  asm volatile("s_waitcnt lgkmcnt(0)" ::: "memory");

  // layer 2
  {
    uint4 bf2[2][2];
#pragma unroll
    for (int nt = 0; nt < 2; ++nt)
#pragma unroll
      for (int kc = 0; kc < 2; ++kc)
        bf2[nt][kc] = *(const uint4*)&Hs[wave][li + 16 * nt][kc * 32 + 8 * g];

    f32x4 acc[4][2];
#pragma unroll
    for (int mt = 0; mt < 4; ++mt) {
      float4 bb = *(const float4*)(b2 + mt * 16 + 4 * g);
      acc[mt][0] = f32x4{bb.x, bb.y, bb.z, bb.w};
      acc[mt][1] = acc[mt][0];
    }
#pragma unroll
    for (int mt = 0; mt < 4; ++mt)
#pragma unroll
      for (int kc = 0; kc < 2; ++kc) {
        uint4 aw = wf4[(WF_L2 >> 3) + (mt * 2 + kc) * 64 + lane];
        s16x8 a = __builtin_bit_cast(s16x8, aw);
        acc[mt][0] = __builtin_amdgcn_mfma_f32_16x16x32_bf16(
            a, __builtin_bit_cast(s16x8, bf2[0][kc]), acc[mt][0], 0, 0, 0);
        acc[mt][1] = __builtin_amdgcn_mfma_f32_16x16x32_bf16(
            a, __builtin_bit_cast(s16x8, bf2[1][kc]), acc[mt][1], 0, 0, 0);
      }
    asm volatile("s_waitcnt lgkmcnt(0)" ::: "memory");
#pragma unroll
    for (int mt = 0; mt < 4; ++mt)
#pragma unroll
      for (int nt = 0; nt < 2; ++nt) {
        f32x4 v = acc[mt][nt];
        u32 w0 = pack2bf(fmaxf(v[0], 0.f), fmaxf(v[1], 0.f));
        u32 w1 = pack2bf(fmaxf(v[2], 0.f), fmaxf(v[3], 0.f));
        *(uint2*)&Hs[wave][li + 16 * nt][mt * 16 + 4 * g] = make_uint2(w0, w1);
      }
  }
  asm volatile("s_waitcnt lgkmcnt(0)" ::: "memory");

  // layer 3 + max over neighbors
  {
    uint4 bf3[2][2];
#pragma unroll
    for (int nt = 0; nt < 2; ++nt)
#pragma unroll
      for (int kc = 0; kc < 2; ++kc)
        bf3[nt][kc] = *(const uint4*)&Hs[wave][li + 16 * nt][kc * 32 + 8 * g];

    f32x4 acc[8][2];
#pragma unroll
    for (int mt = 0; mt < 8; ++mt) {
      float4 bb = *(const float4*)(b3 + mt * 16 + 4 * g);
      acc[mt][0] = f32x4{bb.x, bb.y, bb.z, bb.w};
      acc[mt][1] = acc[mt][0];
    }
#pragma unroll
    for (int mt = 0; mt < 8; ++mt)
#pragma unroll
      for (int kc = 0; kc < 2; ++kc) {
        uint4 aw = wf4[(WF_L3 >> 3) + (mt * 2 + kc) * 64 + lane];
        s16x8 a = __builtin_bit_cast(s16x8, aw);
        acc[mt][0] = __builtin_amdgcn_mfma_f32_16x16x32_bf16(
            a, __builtin_bit_cast(s16x8, bf3[0][kc]), acc[mt][0], 0, 0, 0);
        acc[mt][1] = __builtin_amdgcn_mfma_f32_16x16x32_bf16(
            a, __builtin_bit_cast(s16x8, bf3[1][kc]), acc[mt][1], 0, 0, 0);
      }

    float m[8][4];
#pragma unroll
    for (int mt = 0; mt < 8; ++mt)
#pragma unroll
      for (int r = 0; r < 4; ++r)
        m[mt][r] = fmaxf(acc[mt][0][r], acc[mt][1][r]);

    DPP_FMAX_STAGE(0xB1);
    DPP_FMAX_STAGE(0x4E);
    DPP_FMAX_STAGE(0x141);
    DPP_FMAX_STAGE(0x140);

#pragma unroll
    for (int mt = 0; mt < 8; ++mt) {
      if (li == mt) {
        float4 o = make_float4(m[mt][0], m[mt][1], m[mt][2], m[mt][3]);
        *(float4*)(out + (size_t)q * NOUT + mt * 16 + 4 * g) = o;
      }
    }
  }
}

extern "C" void kernel_launch(void* const* d_in, const int* in_sizes, int n_in,
                              void* d_out, int out_size, void* d_ws, size_t ws_size,
                              hipStream_t stream) {
  (void)in_sizes; (void)n_in; (void)out_size; (void)ws_size;
  const float* x   = (const float*)d_in[0];
  const float* pos = (const float*)d_in[1];
  const float* W1 = (const float*)d_in[3];
  const float* b1 = (const float*)d_in[4];
  const float* W2 = (const float*)d_in[5];
  const float* b2 = (const float*)d_in[6];
  const float* W3 = (const float*)d_in[7];
  const float* b3 = (const float*)d_in[8];

  float* out     = (float*)d_out;
  float* pos_q   = out + (size_t)NB * NS * NOUT;
  float* batch_q = pos_q + (size_t)NB * NS * 3;

  int* nbr = (int*)d_ws;                                        // 2 MB
  u16* wfrag = (u16*)((char*)d_ws + (size_t)NB * NS * NK * 4);  // 36 KB

  hipLaunchKernelGGL(prep_kernel, dim3((WF_TOT + 255) / 256), dim3(256), 0,
                     stream, W1, W2, W3, wfrag);
  hipLaunchKernelGGL(fps_kernel, dim3(NB), dim3(256), 0, stream,
                     pos, pos_q, batch_q);
  hipLaunchKernelGGL(knn_kernel, dim3(NB * NS), dim3(64), 0, stream,
                     pos, pos_q, nbr);
  hipLaunchKernelGGL(conv_kernel, dim3(NB * NS / 4), dim3(256), 0, stream,
                     x, pos, wfrag, b1, b2, b3, nbr, pos_q, out);
}

// Round 15
// 796.859 us; speedup vs baseline: 1.4554x; 1.4554x over previous
//
#include <hip/hip_runtime.h>
#include <math.h>

#define NB   16
#define NP   4096
#define NC   64
#define NS   1024
#define NK   32
#define NOUT 128

typedef unsigned long long u64;
typedef unsigned int u32;
typedef unsigned short u16;
typedef __attribute__((ext_vector_type(8))) short s16x8;
typedef __attribute__((ext_vector_type(4))) float f32x4;

__device__ inline u64 umin64(u64 a, u64 b) { return a < b ? a : b; }
__device__ inline u64 umax64(u64 a, u64 b) { return a > b ? a : b; }

__device__ inline u16 f2bf(float f) {
  u32 x = __float_as_uint(f);
  return (u16)((x + 0x7fffu + ((x >> 16) & 1u)) >> 16);
}
__device__ inline u32 pack2bf(float a, float b) {
  return (u32)f2bf(a) | ((u32)f2bf(b) << 16);
}

__device__ inline float d2exact(float ax, float ay, float az,
                                float qx, float qy, float qz) {
  float dx = __fsub_rn(ax, qx), dy = __fsub_rn(ay, qy), dz = __fsub_rn(az, qz);
  return __fadd_rn(__fadd_rn(__fmul_rn(dx, dx), __fmul_rn(dy, dy)),
                   __fmul_rn(dz, dz));
}

// ---------------------------------------------------------------------------
// DPP wave64 reductions on packed u64 keys (row_shr toward lane15, bcast15,
// bcast31 -> result in lane 63). Verified rounds 5-13.
// ---------------------------------------------------------------------------
#define DPP_LVL_MAX(CTRL)                                                     \
  {                                                                           \
    u32 lo = (u32)key, hi = (u32)(key >> 32);                                 \
    u32 plo = (u32)__builtin_amdgcn_update_dpp((int)lo, (int)lo, CTRL, 0xF, 0xF, false); \
    u32 phi = (u32)__builtin_amdgcn_update_dpp((int)hi, (int)hi, CTRL, 0xF, 0xF, false); \
    u64 ok = ((u64)phi << 32) | plo;                                          \
    key = (ok > key) ? ok : key;                                              \
  }
__device__ inline u64 dpp_wavemax_u64(u64 key) {
  DPP_LVL_MAX(0x111) DPP_LVL_MAX(0x112) DPP_LVL_MAX(0x114)
  DPP_LVL_MAX(0x118) DPP_LVL_MAX(0x142) DPP_LVL_MAX(0x143)
  return key;  // lane 63 valid
}
#define DPP_LVL_MIN(CTRL)                                                     \
  {                                                                           \
    u32 lo = (u32)key, hi = (u32)(key >> 32);                                 \
    u32 plo = (u32)__builtin_amdgcn_update_dpp((int)lo, (int)lo, CTRL, 0xF, 0xF, false); \
    u32 phi = (u32)__builtin_amdgcn_update_dpp((int)hi, (int)hi, CTRL, 0xF, 0xF, false); \
    u64 ok = ((u64)phi << 32) | plo;                                          \
    key = (ok < key) ? ok : key;                                              \
  }
__device__ inline u64 dpp_wavemin_bcast_u64(u64 key) {
  DPP_LVL_MIN(0x111) DPP_LVL_MIN(0x112) DPP_LVL_MIN(0x114)
  DPP_LVL_MIN(0x118) DPP_LVL_MIN(0x142) DPP_LVL_MIN(0x143)
  u32 lo = (u32)__builtin_amdgcn_readlane((int)(u32)key, 63);
  u32 hi = (u32)__builtin_amdgcn_readlane((int)(u32)(key >> 32), 63);
  return ((u64)hi << 32) | lo;  // uniform across wave
}

#define DPP_FMAX_STAGE(CTRL)                                                  \
  do {                                                                        \
    _Pragma("unroll")                                                         \
    for (int mt = 0; mt < 8; ++mt) {                                          \
      _Pragma("unroll")                                                       \
      for (int r = 0; r < 4; ++r) {                                           \
        int vi = __float_as_int(m[mt][r]);                                    \
        int ov = __builtin_amdgcn_update_dpp(vi, vi, CTRL, 0xF, 0xF, false);  \
        m[mt][r] = fmaxf(m[mt][r], __int_as_float(ov));                       \
      }                                                                       \
    }                                                                         \
  } while (0)

__device__ inline void ins4(u64& b0, u64& b1, u64& b2, u64& b3, u64 k) {
  u64 m0 = umax64(b0, k); b0 = umin64(b0, k);
  u64 m1 = umax64(b1, m0); b1 = umin64(b1, m0);
  u64 m2 = umax64(b2, m1); b2 = umin64(b2, m1);
  b3 = umin64(b3, m2);
}

// ---------------------------------------------------------------------------
// FPS: one block per cloud, 256 threads (4 waves, 1/SIMD), 16 pts/thread in
// registers + LDS point cache (for far-point lookup and final output).
// One barrier per step (double-buffered keys); plain u64-key DPP wavemax.
// Local argmax split into two 8-deep chains merged via packed keys (exact
// lowest-index tie-break preserved by key encoding). Bit-exact math.
// NOTE: no global stores inside the serial loop (a vmcnt drain at the
// barrier costs ~400 cyc/step — measured in round 14).
// ---------------------------------------------------------------------------
__global__ __launch_bounds__(256) void fps_kernel(const float* __restrict__ pos,
                                                  float* __restrict__ pos_q,
                                                  float* __restrict__ batch_q) {
  const int b = blockIdx.x;
  const int tid = threadIdx.x;
  const int wave = tid >> 6;
  const float* pb = pos + (size_t)b * NP * 3;

  __shared__ float lx[NP], ly[NP], lz[NP];
  __shared__ u64 s_key[2][4];
  __shared__ int s_idx[NS];

  float px[16], py[16], pz[16], dist[16];
#pragma unroll
  for (int i = 0; i < 16; ++i) {
    int p = i * 256 + tid;
    float xx = pb[p * 3 + 0];
    float yy = pb[p * 3 + 1];
    float zz = pb[p * 3 + 2];
    px[i] = xx; py[i] = yy; pz[i] = zz;
    lx[p] = xx; ly[p] = yy; lz[p] = zz;
    dist[i] = __builtin_inff();
  }
  __syncthreads();

  float fx = lx[0], fy = ly[0], fz = lz[0];
  int far = 0;

  for (int s = 0; s < NS; ++s) {
    if (tid == 0) s_idx[s] = far;

    // two independent 8-deep select chains (even/odd i) -> half the serial
    // dependency depth of the per-thread argmax
    float bva = -1.0f, bvb = -1.0f;
    int bpa = 0, bpb = 0;
#pragma unroll
    for (int i = 0; i < 16; ++i) {
      float dx = __fsub_rn(px[i], fx);
      float dy = __fsub_rn(py[i], fy);
      float dz = __fsub_rn(pz[i], fz);
      float d = __fadd_rn(__fadd_rn(__fmul_rn(dx, dx), __fmul_rn(dy, dy)),
                          __fmul_rn(dz, dz));
      d = fminf(dist[i], d);
      dist[i] = d;
      if (i & 1) {
        if (d > bvb) { bvb = d; bpb = i * 256 + tid; }
      } else {
        if (d > bva) { bva = d; bpa = i * 256 + tid; }
      }
    }
    u64 ka = ((u64)__float_as_uint(bva) << 32) | (u32)(NP - 1 - bpa);
    u64 kb = ((u64)__float_as_uint(bvb) << 32) | (u32)(NP - 1 - bpb);
    u64 key = umax64(ka, kb);

    key = dpp_wavemax_u64(key);
    if ((tid & 63) == 63) s_key[s & 1][wave] = key;
    __syncthreads();

    u64 k0 = s_key[s & 1][0];
    u64 k1 = s_key[s & 1][1];
    u64 k2 = s_key[s & 1][2];
    u64 k3 = s_key[s & 1][3];
    u64 km = umax64(umax64(k0, k1), umax64(k2, k3));
    far = NP - 1 - (int)(u32)(km & 0xFFFFFFFFull);
    fx = lx[far]; fy = ly[far]; fz = lz[far];
  }
  __syncthreads();

  for (int s = tid; s < NS; s += 256) {
    int p = s_idx[s];
    size_t o = (size_t)(b * NS + s);
    pos_q[o * 3 + 0] = lx[p];
    pos_q[o * 3 + 1] = ly[p];
    pos_q[o * 3 + 2] = lz[p];
    batch_q[o] = (float)b;
  }
}

// ---------------------------------------------------------------------------
// kNN: one wave per query (round-7 verbatim, passing). Coalesced float4
// scan, sorted top-4/lane, 32 DPP-min extractions + owner pop, rare refill.
// Owner of point p: lane (p>>2)&63; slot = (p>>8)*4 + (p&3).
// ---------------------------------------------------------------------------
__global__ __launch_bounds__(64) void knn_kernel(const float* __restrict__ pos,
                                                 const float* __restrict__ pos_q,
                                                 int* __restrict__ nbr) {
  const u64 KMAX = ~0ull;
  const int q = blockIdx.x;
  const int b = q >> 10;
  const int lane = threadIdx.x;
  const float* pb = pos + (size_t)b * NP * 3;
  const float qx = pos_q[q * 3 + 0];
  const float qy = pos_q[q * 3 + 1];
  const float qz = pos_q[q * 3 + 2];

  u64 b0 = KMAX, b1 = KMAX, b2 = KMAX, b3 = KMAX;
#pragma unroll 4
  for (int gg = 0; gg < 16; ++gg) {
    int p = gg * 256 + lane * 4;
    const float* s = pb + (size_t)p * 3;
    float4 v0 = *(const float4*)(s);
    float4 v1 = *(const float4*)(s + 4);
    float4 v2 = *(const float4*)(s + 8);
    float d0 = d2exact(v0.x, v0.y, v0.z, qx, qy, qz);
    float d1 = d2exact(v0.w, v1.x, v1.y, qx, qy, qz);
    float d2 = d2exact(v1.z, v1.w, v2.x, qx, qy, qz);
    float d3 = d2exact(v2.y, v2.z, v2.w, qx, qy, qz);
    ins4(b0, b1, b2, b3, ((u64)__float_as_uint(d0) << 32) | (u32)(p + 0));
    ins4(b0, b1, b2, b3, ((u64)__float_as_uint(d1) << 32) | (u32)(p + 1));
    ins4(b0, b1, b2, b3, ((u64)__float_as_uint(d2) << 32) | (u32)(p + 2));
    ins4(b0, b1, b2, b3, ((u64)__float_as_uint(d3) << 32) | (u32)(p + 3));
  }

  u64 exmask = 0ull;
  for (int r = 0; r < NK; ++r) {
    u64 kmin = dpp_wavemin_bcast_u64(b0);
    u32 p = (u32)kmin;
    if (lane == 0) nbr[q * NK + r] = (int)p;
    if (((p >> 2) & 63u) == (u32)lane) {
      b0 = b1; b1 = b2; b2 = b3; b3 = KMAX;
      exmask |= 1ull << (((p >> 8) << 2) | (p & 3u));
      if (b0 == KMAX) {
        for (int gg = 0; gg < 16; ++gg) {
          int pp = gg * 256 + lane * 4;
          const float* s = pb + (size_t)pp * 3;
          float4 v0 = *(const float4*)(s);
          float4 v1 = *(const float4*)(s + 4);
          float4 v2 = *(const float4*)(s + 8);
          float dd[4];
          dd[0] = d2exact(v0.x, v0.y, v0.z, qx, qy, qz);
          dd[1] = d2exact(v0.w, v1.x, v1.y, qx, qy, qz);
          dd[2] = d2exact(v1.z, v1.w, v2.x, qx, qy, qz);
          dd[3] = d2exact(v2.y, v2.z, v2.w, qx, qy, qz);
#pragma unroll
          for (int rr = 0; rr < 4; ++rr) {
            int slot = gg * 4 + rr;
            if ((exmask >> slot) & 1ull) continue;
            ins4(b0, b1, b2, b3,
                 ((u64)__float_as_uint(dd[rr]) << 32) | (u32)(pp + rr));
          }
        }
      }
    }
  }
}

// ---------------------------------------------------------------------------
// Weight prepack (round-7 verbatim): W -> bf16 MFMA A-fragments in d_ws.
// ---------------------------------------------------------------------------
#define WF_L2 6144
#define WF_L3 10240
#define WF_TOT 18432

__global__ __launch_bounds__(256) void prep_kernel(
    const float* __restrict__ W1, const float* __restrict__ W2,
    const float* __restrict__ W3, u16* __restrict__ wf) {
  int flat = blockIdx.x * 256 + threadIdx.x;
  if (flat >= WF_TOT) return;
  float val;
  int j = flat & 7, lane = (flat >> 3) & 63, t = flat >> 9;
  int k8 = 8 * (lane >> 4) + j, li = lane & 15;
  if (flat < WF_L2) {
    int kc = t % 3, mt = t / 3;
    int k = kc * 32 + k8;
    val = (k < 67) ? W1[k * 64 + mt * 16 + li] : 0.0f;
  } else if (flat < WF_L3) {
    t -= WF_L2 >> 9;
    int kc = t & 1, mt = t >> 1;
    val = W2[(kc * 32 + k8) * 64 + mt * 16 + li];
  } else {
    t -= WF_L3 >> 9;
    int kc = t & 1, mt = t >> 1;
    val = W3[(kc * 32 + k8) * 128 + mt * 16 + li];
  }
  wf[flat] = f2bf(val);
}

// ---------------------------------------------------------------------------
// PointNetConv via MFMA 16x16x32 bf16 (round-7 verbatim, passing).
// One query per wave, 4 waves/block, wave-private LDS bounce between layers.
// ---------------------------------------------------------------------------
#define HST 72

__global__ __launch_bounds__(256) void conv_kernel(
    const float* __restrict__ x, const float* __restrict__ pos,
    const u16* __restrict__ wf,
    const float* __restrict__ b1, const float* __restrict__ b2,
    const float* __restrict__ b3,
    const int* __restrict__ nbr, const float* __restrict__ pos_q,
    float* __restrict__ out) {
  __shared__ u16 Hs[4][32][HST];

  const int tid = threadIdx.x, wave = tid >> 6, lane = tid & 63;
  const int q = blockIdx.x * 4 + wave;
  const int b = q >> 10;
  const int g = lane >> 4, li = lane & 15;

  const int n0 = nbr[q * NK + li];
  const int n1 = nbr[q * NK + li + 16];
  const float qx = pos_q[q * 3 + 0];
  const float qy = pos_q[q * 3 + 1];
  const float qz = pos_q[q * 3 + 2];

  uint4 bf1[2][3];
  {
    const float* xb = x + (size_t)b * NP * NC;
#pragma unroll
    for (int nt = 0; nt < 2; ++nt) {
      const float* s = xb + (size_t)(nt ? n1 : n0) * NC + 8 * g;
#pragma unroll
      for (int kc = 0; kc < 2; ++kc) {
        float4 v0 = *(const float4*)(s + kc * 32);
        float4 v1 = *(const float4*)(s + kc * 32 + 4);
        bf1[nt][kc] = make_uint4(pack2bf(v0.x, v0.y), pack2bf(v0.z, v0.w),
                                 pack2bf(v1.x, v1.y), pack2bf(v1.z, v1.w));
      }
      const float* pp = pos + ((size_t)b * NP + (nt ? n1 : n0)) * 3;
      float rx = __fsub_rn(pp[0], qx);
      float ry = __fsub_rn(pp[1], qy);
      float rz = __fsub_rn(pp[2], qz);
      uint4 w = make_uint4(0u, 0u, 0u, 0u);
      if (g == 0) { w.x = pack2bf(rx, ry); w.y = pack2bf(rz, 0.0f); }
      bf1[nt][2] = w;
    }
  }

  const uint4* wf4 = (const uint4*)wf;

  // layer 1
  {
    f32x4 acc[4][2];
#pragma unroll
    for (int mt = 0; mt < 4; ++mt) {
      float4 bb = *(const float4*)(b1 + mt * 16 + 4 * g);
      acc[mt][0] = f32x4{bb.x, bb.y, bb.z, bb.w};
      acc[mt][1] = acc[mt][0];
    }
#pragma unroll
    for (int mt = 0; mt < 4; ++mt)
#pragma unroll
      for (int kc = 0; kc < 3; ++kc) {
        uint4 aw = wf4[(mt * 3 + kc) * 64 + lane];
        s16x8 a = __builtin_bit_cast(s16x8, aw);
        acc[mt][0] = __builtin_amdgcn_mfma_f32_16x16x32_bf16(
            a, __builtin_bit_cast(s16x8, bf1[0][kc]), acc[mt][0], 0, 0, 0);
        acc[mt][1] = __builtin_amdgcn_mfma_f32_16x16x32_bf16(
            a, __builtin_bit_cast(s16x8, bf1[1][kc]), acc[mt][1], 0, 0, 0);
      }
#pragma unroll
    for (int mt = 0; mt < 4; ++mt)
#pragma unroll
      for (int nt = 0; nt < 2; ++nt) {
        f32x4 v = acc[mt][nt];
        u32 w0 = pack2bf(fmaxf(v[0], 0.f), fmaxf(v[1], 0.f));
        u32 w1 = pack2bf(fmaxf(v[2], 0.f), fmaxf(v[3], 0.f));
        *(uint2*)&Hs[wave][li + 16 * nt][mt * 16 + 4 * g] = make_uint2(w0, w1);
      }
  }
  asm volatile("s_waitcnt lgkmcnt(0)" ::: "memory");

  // layer 2
  {
    uint4 bf2[2][2];
#pragma unroll
    for (int nt = 0; nt < 2; ++nt)
#pragma unroll
      for (int kc = 0; kc < 2; ++kc)
        bf2[nt][kc] = *(const uint4*)&Hs[wave][li + 16 * nt][kc * 32 + 8 * g];

    f32x4 acc[4][2];
#pragma unroll
    for (int mt = 0; mt < 4; ++mt) {
      float4 bb = *(const float4*)(b2 + mt * 16 + 4 * g);
      acc[mt][0] = f32x4{bb.x, bb.y, bb.z, bb.w};
      acc[mt][1] = acc[mt][0];
    }
#pragma unroll
    for (int mt = 0; mt < 4; ++mt)
#pragma unroll
      for (int kc = 0; kc < 2; ++kc) {
        uint4 aw = wf4[(WF_L2 >> 3) + (mt * 2 + kc) * 64 + lane];
        s16x8 a = __builtin_bit_cast(s16x8, aw);
        acc[mt][0] = __builtin_amdgcn_mfma_f32_16x16x32_bf16(
            a, __builtin_bit_cast(s16x8, bf2[0][kc]), acc[mt][0], 0, 0, 0);
        acc[mt][1] = __builtin_amdgcn_mfma_f32_16x16x32_bf16(
            a, __builtin_bit_cast(s16x8, bf2[1][kc]), acc[mt][1], 0, 0, 0);
      }
    asm volatile("s_waitcnt lgkmcnt(0)" ::: "memory");
#pragma unroll
    for (int mt = 0; mt < 4; ++mt)
#pragma unroll
      for (int nt = 0; nt < 2; ++nt) {
        f32x4 v = acc[mt][nt];
        u32 w0 = pack2bf(fmaxf(v[0], 0.f), fmaxf(v[1], 0.f));
        u32 w1 = pack2bf(fmaxf(v[2], 0.f), fmaxf(v[3], 0.f));
        *(uint2*)&Hs[wave][li + 16 * nt][mt * 16 + 4 * g] = make_uint2(w0, w1);
      }
  }
  asm volatile("s_waitcnt lgkmcnt(0)" ::: "memory");

  // layer 3 + max over neighbors
  {
    uint4 bf3[2][2];
#pragma unroll
    for (int nt = 0; nt < 2; ++nt)
#pragma unroll
      for (int kc = 0; kc < 2; ++kc)
        bf3[nt][kc] = *(const uint4*)&Hs[wave][li + 16 * nt][kc * 32 + 8 * g];

    f32x4 acc[8][2];
#pragma unroll
    for (int mt = 0; mt < 8; ++mt) {
      float4 bb = *(const float4*)(b3 + mt * 16 + 4 * g);
      acc[mt][0] = f32x4{bb.x, bb.y, bb.z, bb.w};
      acc[mt][1] = acc[mt][0];
    }
#pragma unroll
    for (int mt = 0; mt < 8; ++mt)
#pragma unroll
      for (int kc = 0; kc < 2; ++kc) {
        uint4 aw = wf4[(WF_L3 >> 3) + (mt * 2 + kc) * 64 + lane];
        s16x8 a = __builtin_bit_cast(s16x8, aw);
        acc[mt][0] = __builtin_amdgcn_mfma_f32_16x16x32_bf16(
            a, __builtin_bit_cast(s16x8, bf3[0][kc]), acc[mt][0], 0, 0, 0);
        acc[mt][1] = __builtin_amdgcn_mfma_f32_16x16x32_bf16(
            a, __builtin_bit_cast(s16x8, bf3[1][kc]), acc[mt][1], 0, 0, 0);
      }

    float m[8][4];
#pragma unroll
    for (int mt = 0; mt < 8; ++mt)
#pragma unroll
      for (int r = 0; r < 4; ++r)
        m[mt][r] = fmaxf(acc[mt][0][r], acc[mt][1][r]);

    DPP_FMAX_STAGE(0xB1);
    DPP_FMAX_STAGE(0x4E);
    DPP_FMAX_STAGE(0x141);
    DPP_FMAX_STAGE(0x140);

#pragma unroll
    for (int mt = 0; mt < 8; ++mt) {
      if (li == mt) {
        float4 o = make_float4(m[mt][0], m[mt][1], m[mt][2], m[mt][3]);
        *(float4*)(out + (size_t)q * NOUT + mt * 16 + 4 * g) = o;
      }
    }
  }
}

extern "C" void kernel_launch(void* const* d_in, const int* in_sizes, int n_in,
                              void* d_out, int out_size, void* d_ws, size_t ws_size,
                              hipStream_t stream) {
  (void)in_sizes; (void)n_in; (void)out_size; (void)ws_size;
  const float* x   = (const float*)d_in[0];
  const float* pos = (const float*)d_in[1];
  const float* W1 = (const float*)d_in[3];
  const float* b1 = (const float*)d_in[4];
  const float* W2 = (const float*)d_in[5];
  const float* b2 = (const float*)d_in[6];
  const float* W3 = (const float*)d_in[7];
  const float* b3 = (const float*)d_in[8];

  float* out     = (float*)d_out;
  float* pos_q   = out + (size_t)NB * NS * NOUT;
  float* batch_q = pos_q + (size_t)NB * NS * 3;

  int* nbr = (int*)d_ws;                                        // 2 MB
  u16* wfrag = (u16*)((char*)d_ws + (size_t)NB * NS * NK * 4);  // 36 KB

  hipLaunchKernelGGL(prep_kernel, dim3((WF_TOT + 255) / 256), dim3(256), 0,
                     stream, W1, W2, W3, wfrag);
  hipLaunchKernelGGL(fps_kernel, dim3(NB), dim3(256), 0, stream,
                     pos, pos_q, batch_q);
  hipLaunchKernelGGL(knn_kernel, dim3(NB * NS), dim3(64), 0, stream,
                     pos, pos_q, nbr);
  hipLaunchKernelGGL(conv_kernel, dim3(NB * NS / 4), dim3(256), 0, stream,
                     x, pos, wfrag, b1, b2, b3, nbr, pos_q, out);
}